// Round 10
// baseline (624.093 us; speedup 1.0000x reference)
//
#include <hip/hip_runtime.h>
#include <hip/hip_bf16.h>
#include <stdint.h>

// GraphInterConnection P=16,B=4,C=256,N=256.  R10: async-pipelined MFMA.
//   corr[j,d]=sum_c tf_p[c,j]We[d,c]; A[j,i]=sum_d corr[j,d]tf_q[d,i]
//   S=softmax_i(A[j,:]); g_q[i]=sum_c Wg[c]tf_q[c,i]
//   mask[j]=sigmoid(sum_i S[j,i]g_q[i]);  W=mask*S
//   out[p,b,c,j]=(1/pn)*sum_q sum_i W[j,i]tf_q[c,i]   (fp32 out)
// Staging via global_load_lds(16B) + prefetch-after-barrier dbuf (m97 pattern).
// tfT/th stored PRE-TILED in ws so LDS reads are lane-contiguous (no swizzle
// needed, conflict-free) and g_l_l sources are 1KB-contiguous per wave.
// Tile (16 rows x 256 k): elem[row][k] at blk=(k/8)*16+row, addr=blk*8+(k%8)
//   -> frag read = base + kk*512 + lane*8 (shorts).
// M1 = 2-chain (corr hi/lo x tfT hi); M2 = 1-chain. W bf16 (0.0039 proven).

#define NP 16
#define NB 4
#define NC 256
#define NN 256
#define SLAB 65536

typedef __attribute__((ext_vector_type(8))) short bf16x8;
typedef __attribute__((ext_vector_type(4))) float f32x4;
typedef __attribute__((ext_vector_type(4))) float f4;

static __device__ __forceinline__ float b2f(unsigned short u) {
  union { unsigned u; float f; } x; x.u = ((unsigned)u) << 16; return x.f;
}
static __device__ __forceinline__ unsigned short f2b(float f) {
  unsigned u = __float_as_uint(f);
  u += 0x7fffu + ((u >> 16) & 1u);
  return (unsigned short)(u >> 16);
}
static __device__ __forceinline__ int is_bf16(const void* p) {
  const unsigned short* s = (const unsigned short*)p;
  int sane = 0;
  for (int i = 0; i < 64; ++i) {
    float av = fabsf(b2f(s[i]));
    sane += ((av == 0.0f) || (av > 8e-13f && av < 256.0f)) ? 1 : 0;
  }
  return sane >= 56;
}
static __device__ __forceinline__ f4 ld4(const void* p, size_t idx, int isb) {
  if (isb) {
    ushort4 v = *(const ushort4*)((const unsigned short*)p + idx);
    f4 r; r[0] = b2f(v.x); r[1] = b2f(v.y); r[2] = b2f(v.z); r[3] = b2f(v.w);
    return r;
  }
  return *(const f4*)((const float*)p + idx);
}
static __device__ __forceinline__ float ld1(const void* p, size_t idx, int isb) {
  return isb ? b2f(((const unsigned short*)p)[idx]) : ((const float*)p)[idx];
}
static __device__ __forceinline__ float read_pn(const void* p) {
  int iv = *(const int*)p;
  if (iv >= 1 && iv <= 65536) return (float)iv;
  float fv = *(const float*)p;
  if (fv >= 1.0f && fv <= 65536.0f) return fv;
  return 16.0f;
}
static __device__ __forceinline__ void async16(const void* g, void* l) {
  __builtin_amdgcn_global_load_lds((const __attribute__((address_space(1))) void*)g,
                                   (__attribute__((address_space(3))) void*)l, 16, 0, 0);
}

// ---- k_conv: We -> hi/lo bf16; Wg -> fp32. grid 33. ----------------------
__global__ __launch_bounds__(256, 1)
void k_conv(const void* wev, const void* wgv,
            unsigned short* __restrict__ weh, unsigned short* __restrict__ wel,
            float* __restrict__ wgf)
{
  const int bx = blockIdx.x, tid = threadIdx.x;
  if (bx < 32) {
    const int eb = is_bf16(wev);
    const size_t base = (size_t)bx * 2048 + tid * 8;
    bf16x8 h, l;
#pragma unroll
    for (int s = 0; s < 2; ++s) {
      f4 v = ld4(wev, base + s * 4, eb);
#pragma unroll
      for (int k = 0; k < 4; ++k) {
        unsigned short hi = f2b(v[k]);
        h[s * 4 + k] = (short)hi;
        l[s * 4 + k] = (short)f2b(v[k] - b2f(hi));
      }
    }
    *(bf16x8*)(weh + base) = h;
    *(bf16x8*)(wel + base) = l;
  } else {
    if (tid < 64) {
      const int gb = is_bf16(wgv);
      f4 v = ld4(wgv, tid * 4, gb);
      *(f4*)(wgf + tid * 4) = v;
    }
  }
}

// ---- k_prep: per (pb, cb of 32 i-rows): transpose, tiled tfT-hi, tiled th,
//              g partials, corr hi/lo (3-chain MFMA). grid 512. -------------
__global__ __launch_bounds__(256, 1)
void k_prep(const void* __restrict__ tempv,
            const unsigned short* __restrict__ weh, const unsigned short* __restrict__ wel,
            const float* __restrict__ wgf,
            unsigned short* __restrict__ tfTh_t, unsigned short* __restrict__ th_t,
            unsigned short* __restrict__ corrh, unsigned short* __restrict__ corrl,
            float* __restrict__ gws)
{
  __shared__ float smT[32 * 264];   // [i-local][c]
  __shared__ float gpart[256];
  const int bx = blockIdx.x;
  const int pb = bx >> 3, cb = bx & 7;
  const int tid = threadIdx.x;
  const int lane = tid & 63, wave = tid >> 6;
  const int l15 = lane & 15, quad = lane >> 4;
  const int tb = is_bf16(tempv);

  // stage: temp[pb][c=tid][cb*32 + il] -> smT[il][c]
#pragma unroll
  for (int s = 0; s < 8; ++s) {
    f4 v = ld4(tempv, (size_t)pb * SLAB + (size_t)tid * NN + cb * 32 + s * 4, tb);
#pragma unroll
    for (int w = 0; w < 4; ++w) smT[(s * 4 + w) * 264 + tid] = v[w];
  }
  __syncthreads();

  // A) tfT tiled hi: tiles ic = 2cb+icl; blk=(d/8)*16+r <- smT[icl*16+r][d]
#pragma unroll
  for (int s = 0; s < 4; ++s) {
    int cid = s * 256 + tid;
    int icl = cid >> 9, blk = cid & 511;
    int c8 = blk >> 4, r = blk & 15;
    const float* src = smT + (icl * 16 + r) * 264 + c8 * 8;
    bf16x8 h;
#pragma unroll
    for (int e = 0; e < 8; ++e) h[e] = (short)f2b(src[e]);
    *(bf16x8*)(tfTh_t + (size_t)pb * SLAB + (size_t)(cb * 2 + icl) * 4096 + blk * 8) = h;
  }

  // B) th tiled hi: tile (mc, st): blk=(i/8)*16 + c%16; this block owns i8 = cb*4..+4
#pragma unroll
  for (int s = 0; s < 4; ++s) {
    int cid = s * 256 + tid;
    int grp = cid >> 4, r = cid & 15;
    int mc = grp >> 3, st = (grp >> 2) & 1, c8l = grp & 3;
    int c = mc * 32 + st * 16 + r;
    bf16x8 h;
#pragma unroll
    for (int e = 0; e < 8; ++e) h[e] = (short)f2b(smT[(c8l * 8 + e) * 264 + c]);
    size_t dst = (size_t)pb * SLAB + mc * 8192 + st * 4096 + ((size_t)((cb * 4 + c8l) * 16 + r)) * 8;
    *(bf16x8*)(th_t + dst) = h;
  }

  // C) g partials
  {
    const int row = tid >> 3, grp = tid & 7;
    float a = 0.f;
#pragma unroll
    for (int u = 0; u < 32; ++u) {
      int c = grp * 32 + u;
      a = fmaf(smT[row * 264 + c], wgf[c], a);
    }
    gpart[tid] = a;
  }
  __syncthreads();
  if (tid < 32) {
    float g = 0.f;
#pragma unroll
    for (int k = 0; k < 8; ++k) g += gpart[tid * 8 + k];
    gws[pb * NN + cb * 32 + tid] = g;
  }

  // D) corr[j,d] = sum_c tf[c,j]We[d,c] (3-chain split). wave -> (jt, dhalf)
  {
    const int jt = wave & 1, dh = wave >> 1;
    bf16x8 ah[8], al[8];
#pragma unroll
    for (int kk = 0; kk < 8; ++kk) {
#pragma unroll
      for (int e = 0; e < 8; ++e) {
        float v = smT[(jt * 16 + l15) * 264 + kk * 32 + quad * 8 + e];
        unsigned short hi = f2b(v);
        ah[kk][e] = (short)hi;
        al[kk][e] = (short)f2b(v - b2f(hi));
      }
    }
    for (int dt = 0; dt < 8; ++dt) {
      const int dbase = dh * 128 + dt * 16;
      f32x4 acc = {0.f, 0.f, 0.f, 0.f};
#pragma unroll
      for (int kk = 0; kk < 8; ++kk) {
        bf16x8 bh = *(const bf16x8*)(weh + (size_t)(dbase + l15) * NC + kk * 32 + quad * 8);
        bf16x8 bl = *(const bf16x8*)(wel + (size_t)(dbase + l15) * NC + kk * 32 + quad * 8);
        acc = __builtin_amdgcn_mfma_f32_16x16x32_bf16(al[kk], bh, acc, 0, 0, 0);
        acc = __builtin_amdgcn_mfma_f32_16x16x32_bf16(ah[kk], bl, acc, 0, 0, 0);
        acc = __builtin_amdgcn_mfma_f32_16x16x32_bf16(ah[kk], bh, acc, 0, 0, 0);
      }
#pragma unroll
      for (int r = 0; r < 4; ++r) {
        int j = cb * 32 + jt * 16 + quad * 4 + r;
        int d = dbase + l15;
        unsigned short hi = f2b(acc[r]);
        float lo = acc[r] - b2f(hi);
        size_t off = (size_t)pb * SLAB + (size_t)j * NC + d;
        corrh[off] = hi;
        corrl[off] = f2b(lo);
      }
    }
  }
}

// ---- k_main: pipelined MFMA attention. grid 512 = g(8)*64 + pb. ----------
// LDS: stage 2x16KB + Wball 32KB + gq 1KB = 66,560 B (2 blocks/CU).
__global__ __launch_bounds__(256, 2)
void k_main(const unsigned short* __restrict__ th_t,
            const unsigned short* __restrict__ tfTh_t,
            const unsigned short* __restrict__ corrh, const unsigned short* __restrict__ corrl,
            const float* __restrict__ gws, const void* __restrict__ pnv,
            float* __restrict__ out)
{
  __shared__ unsigned short stage[2][8192];     // 16KB each, pre-tiled chunks
  __shared__ unsigned short Wball[4 * 4096];    // per-wave W[16j][256i], swizzled
  __shared__ float gq[256];
  const int bx = blockIdx.x;
  const int pb = bx & 63;                       // low bits -> XCD affinity
  const int b  = pb & 3;
  const int g  = bx >> 6;
  const int jt = g >> 1, qh = g & 1;
  const int tid = threadIdx.x;
  const int lane = tid & 63, wave = tid >> 6;
  const int l15 = lane & 15, quad = lane >> 4;
  const int jbaseW = jt * 64 + wave * 16;
  unsigned short* Wb = Wball + wave * 4096;

  // resident corr A-frags (hi/lo)
  bf16x8 chf[8], clf[8];
#pragma unroll
  for (int kk = 0; kk < 8; ++kk) {
    size_t off = (size_t)pb * SLAB + (size_t)(jbaseW + l15) * NC + kk * 32 + quad * 8;
    chf[kk] = *(const bf16x8*)(corrh + off);
    clf[kk] = *(const bf16x8*)(corrl + off);
  }

  const f32x4 fz = {0.f, 0.f, 0.f, 0.f};
  f32x4 outacc[16], Aacc[16];
#pragma unroll
  for (int t = 0; t < 16; ++t) outacc[t] = fz;
  bf16x8 wf[8];
  const float inv = 1.0f / read_pn(pnv);

  // chunk cc in [0,128): q = qh*8 + cc>>4; ph = cc&15 (0-7 M1 tfT, 8-15 M2 th)
  auto issue = [&](int cc) {
    const int nq = qh * 8 + (cc >> 4), ph = cc & 15;
    const unsigned short* src = (ph < 8)
        ? tfTh_t + (size_t)(nq * NB + b) * SLAB + ph * 8192
        : th_t   + (size_t)(nq * NB + b) * SLAB + (ph - 8) * 8192;
    unsigned short* buf = stage[cc & 1];
#pragma unroll
    for (int t = 0; t < 4; ++t) {
      int seg = wave * 4 + t;                 // 16 segs x 1KB
      async16(src + seg * 512 + lane * 8, buf + seg * 512);
    }
  };

  issue(0);
  for (int cc = 0; cc < 128; ++cc) {
    const int q = qh * 8 + (cc >> 4), ph = cc & 15;
    __syncthreads();                          // drains vmcnt -> chunk cc landed
    if (cc + 1 < 128) issue(cc + 1);          // prefetch overlaps this chunk's MFMAs
    const unsigned short* buf = stage[cc & 1];

    if (ph == 0) {
      gq[tid] = gws[(q * NB + b) * NN + tid];
#pragma unroll
      for (int t = 0; t < 16; ++t) Aacc[t] = fz;
    }

    if (ph < 8) {
      // M1: chunk = 2 i-tiles; A[16j x 32i] += (corr_hi+corr_lo) @ tfT_hi
#pragma unroll
      for (int it = 0; it < 2; ++it) {
        const int tg = ph * 2 + it;
#pragma unroll
        for (int kk = 0; kk < 8; ++kk) {
          bf16x8 bfr = *(const bf16x8*)(buf + it * 4096 + kk * 512 + lane * 8);
          Aacc[tg] = __builtin_amdgcn_mfma_f32_16x16x32_bf16(clf[kk], bfr, Aacc[tg], 0, 0, 0);
          Aacc[tg] = __builtin_amdgcn_mfma_f32_16x16x32_bf16(chf[kk], bfr, Aacc[tg], 0, 0, 0);
        }
      }
    } else {
      if (ph == 8) {
        // softmax over i + fused gate; W = mask*S -> Wb (bf16, XOR-swizzled)
#pragma unroll
        for (int r = 0; r < 4; ++r) {
          float m = -1e30f;
#pragma unroll
          for (int t = 0; t < 16; ++t) m = fmaxf(m, Aacc[t][r]);
          m = fmaxf(m, __shfl_xor(m, 1)); m = fmaxf(m, __shfl_xor(m, 2));
          m = fmaxf(m, __shfl_xor(m, 4)); m = fmaxf(m, __shfl_xor(m, 8));
          float z = 0.f, s = 0.f;
#pragma unroll
          for (int t = 0; t < 16; ++t) {
            float e = __expf(Aacc[t][r] - m);
            Aacc[t][r] = e;
            z += e;
            s = fmaf(e, gq[t * 16 + l15], s);
          }
          z += __shfl_xor(z, 1); z += __shfl_xor(z, 2); z += __shfl_xor(z, 4); z += __shfl_xor(z, 8);
          s += __shfl_xor(s, 1); s += __shfl_xor(s, 2); s += __shfl_xor(s, 4); s += __shfl_xor(s, 8);
          float rz = 1.f / z;
          float mask = 1.f / (1.f + __expf(-s * rz));
          float sc = mask * rz;
          const int jr = quad * 4 + r;
#pragma unroll
          for (int t = 0; t < 16; ++t) {
            int col = t * 16 + l15;
            int cbk = col >> 3, e = col & 7;
            Wb[jr * 256 + ((cbk ^ jr) * 8) + e] = f2b(Aacc[t][r] * sc);
          }
        }
        // B-frags of W (wave-private; same-wave DS ordered)
#pragma unroll
        for (int kk = 0; kk < 8; ++kk) {
          int kb = kk * 4 + quad;
          wf[kk] = *(const bf16x8*)(Wb + l15 * 256 + ((kb ^ l15) * 8));
        }
      }
      // M2: chunk = 2 c-tiles; outacc[32c x 16j] += tf_q @ W^T
#pragma unroll
      for (int ct = 0; ct < 2; ++ct) {
        const int tg = (ph - 8) * 2 + ct;
#pragma unroll
        for (int kk = 0; kk < 8; ++kk) {
          bf16x8 afr = *(const bf16x8*)(buf + ct * 4096 + kk * 512 + lane * 8);
          outacc[tg] = __builtin_amdgcn_mfma_f32_16x16x32_bf16(afr, wf[kk], outacc[tg], 0, 0, 0);
        }
      }
    }
  }

  // epilogue: fp32 atomic accumulate (qh pair shares outputs)
#pragma unroll
  for (int t = 0; t < 16; ++t) {
#pragma unroll
    for (int r = 0; r < 4; ++r) {
      int c = t * 16 + quad * 4 + r;
      int j = jbaseW + l15;
      atomicAdd(out + ((size_t)pb * NC + c) * NN + j, outacc[t][r] * inv);
    }
  }
}

extern "C" void kernel_launch(void* const* d_in, const int* in_sizes, int n_in,
                              void* d_out, int out_size, void* d_ws, size_t ws_size,
                              hipStream_t stream) {
  const void* temp = nullptr; const void* We = nullptr;
  const void* Wg = nullptr;   const void* pn = nullptr;
  for (int i = 0; i < n_in; ++i) {
    switch (in_sizes[i]) {
      case 4194304: temp = d_in[i]; break;
      case 65536:   We   = d_in[i]; break;
      case 256:     Wg   = d_in[i]; break;
      case 1:       pn   = d_in[i]; break;
      default: break;
    }
  }
  if (!temp) temp = d_in[0];
  if (!We)   We   = d_in[1];
  if (!Wg)   Wg   = d_in[2];
  if (!pn)   pn   = d_in[3];

  char* ws = (char*)d_ws;
  unsigned short* tfTh_t = (unsigned short*)(ws);              //  8 MB tiled [pb][ic][4096]
  unsigned short* th_t   = (unsigned short*)(ws +  8388608);   //  8 MB tiled [pb][mc][8192]
  unsigned short* corrh  = (unsigned short*)(ws + 16777216);   //  8 MB [pb][j][d] hi
  unsigned short* corrl  = (unsigned short*)(ws + 25165824);   //  8 MB [pb][j][d] lo
  unsigned short* weh    = (unsigned short*)(ws + 33554432);   // 128 KB
  unsigned short* wel    = (unsigned short*)(ws + 33685504);   // 128 KB
  float*          gws    = (float*)         (ws + 33816576);   //  64 KB
  float*          wgf    = (float*)         (ws + 33882112);   //   1 KB

  hipMemsetAsync(d_out, 0, (size_t)out_size * sizeof(float), stream);
  hipLaunchKernelGGL(k_conv, dim3(33), dim3(256), 0, stream, We, Wg, weh, wel, wgf);
  hipLaunchKernelGGL(k_prep, dim3(512), dim3(256), 0, stream,
                     temp, weh, wel, wgf, tfTh_t, th_t, corrh, corrl, gws);
  hipLaunchKernelGGL(k_main, dim3(512), dim3(256), 0, stream,
                     th_t, tfTh_t, corrh, corrl, gws, pn, (float*)d_out);
}